// Round 1
// baseline (170.126 us; speedup 1.0000x reference)
//
#include <hip/hip_runtime.h>
#include <math.h>

#define ALPHA 0.2f

constexpr int CN0 = 512, CN1 = 2048, CN2 = 8192, CK = 33;
constexpr int CIN = 256, CHID = 128, CNH = 8;

// ---------------------------------------------------------------------------
// Tiled f32 GEMM: C[M,N] = A[M,Kdim] * B
// MODE 0: B is W1 [NH][IN][HID]; logical B[k][col] = W1[col>>7][k][col&127]
// MODE 1: B is plain row-major [Kdim][N]
// tile 64x64, BK=16, 256 threads, 4x4 per thread
// ---------------------------------------------------------------------------
template <int MODE>
__global__ __launch_bounds__(256) void gemm_tile(const float* __restrict__ A,
                                                 const float* __restrict__ B,
                                                 float* __restrict__ C,
                                                 int M, int N, int Kdim) {
    __shared__ float As[16][68];  // [k][row], pad 68 breaks bank conflicts
    __shared__ float Bs[16][68];  // [k][col]

    const int tid  = threadIdx.x;
    const int row0 = blockIdx.x * 64;
    const int col0 = blockIdx.y * 64;

    const int tr = tid >> 4;   // 0..15 -> rows tr*4..tr*4+3
    const int tc = tid & 15;   // 0..15 -> cols tc*4..tc*4+3

    const int ar = tid >> 2;          // 0..63  (A tile row)
    const int ac = (tid & 3) << 2;    // 0,4,8,12 (A tile k)
    const int br = tid >> 4;          // 0..15  (B tile k)
    const int bc = (tid & 15) << 2;   // 0..60  (B tile col)

    float acc[4][4] = {};

    for (int k0 = 0; k0 < Kdim; k0 += 16) {
        // ---- stage A (64x16) ----
        const float4 av = *reinterpret_cast<const float4*>(
            A + (size_t)(row0 + ar) * Kdim + k0 + ac);
        As[ac + 0][ar] = av.x;
        As[ac + 1][ar] = av.y;
        As[ac + 2][ar] = av.z;
        As[ac + 3][ar] = av.w;

        // ---- stage B (16x64) ----
        const int col = col0 + bc;
        const float* bp;
        if (MODE == 0) {
            bp = B + ((size_t)(col >> 7) << 15) + (size_t)(k0 + br) * CHID + (col & 127);
        } else {
            bp = B + (size_t)(k0 + br) * N + col;
        }
        *reinterpret_cast<float4*>(&Bs[br][bc]) = *reinterpret_cast<const float4*>(bp);

        __syncthreads();

#pragma unroll
        for (int kk = 0; kk < 16; ++kk) {
            const float4 a4 = *reinterpret_cast<const float4*>(&As[kk][tr * 4]);
            const float4 b4 = *reinterpret_cast<const float4*>(&Bs[kk][tc * 4]);
            const float aa[4] = {a4.x, a4.y, a4.z, a4.w};
            const float bb[4] = {b4.x, b4.y, b4.z, b4.w};
#pragma unroll
            for (int i = 0; i < 4; ++i)
#pragma unroll
                for (int j = 0; j < 4; ++j) acc[i][j] = fmaf(aa[i], bb[j], acc[i][j]);
        }
        __syncthreads();
    }

#pragma unroll
    for (int i = 0; i < 4; ++i) {
        float4 o = make_float4(acc[i][0], acc[i][1], acc[i][2], acc[i][3]);
        *reinterpret_cast<float4*>(C + (size_t)(row0 + tr * 4 + i) * N + col0 + tc * 4) = o;
    }
}

// ---------------------------------------------------------------------------
// Per-(head,node) attention scores: s1 = h . a[:HID], s2 = h . a[HID:]
// one 64-lane wave per (head, node); h row is 128 f32 (2 per lane)
// ---------------------------------------------------------------------------
__global__ __launch_bounds__(256) void scores_k(const float* __restrict__ hm,
                                                const float* __restrict__ a,
                                                float* __restrict__ s1,
                                                float* __restrict__ s2,
                                                int nnodes, int nheads, int rowstride) {
    const int wid  = (blockIdx.x * blockDim.x + threadIdx.x) >> 6;
    const int lane = threadIdx.x & 63;
    if (wid >= nnodes * nheads) return;
    const int head = wid / nnodes;
    const int node = wid - head * nnodes;

    const float* hrow = hm + (size_t)node * rowstride + head * CHID;
    const float* ah   = a + head * 2 * CHID;

    const int j = lane * 2;
    const float2 hv = *reinterpret_cast<const float2*>(hrow + j);
    float d1 = hv.x * ah[j] + hv.y * ah[j + 1];
    float d2 = hv.x * ah[CHID + j] + hv.y * ah[CHID + j + 1];

#pragma unroll
    for (int m = 1; m < 64; m <<= 1) {
        d1 += __shfl_xor(d1, m);
        d2 += __shfl_xor(d2, m);
    }
    if (lane == 0) {
        s1[(size_t)head * nnodes + node] = d1;
        s2[(size_t)head * nnodes + node] = d2;
    }
}

// ---------------------------------------------------------------------------
// Softmax over K=33 edges of one target + weighted aggregate of h[dst] + ELU
// block = 128 threads; grid = (ntargets, nheads)
// ---------------------------------------------------------------------------
__global__ __launch_bounds__(128) void agg_k(const float* __restrict__ s1,
                                             const float* __restrict__ s2,
                                             const int* __restrict__ src,
                                             const int* __restrict__ dst,
                                             const float* __restrict__ hm,
                                             float* __restrict__ out,
                                             int nnodes, int rowstride, int outstride) {
    __shared__ float wgt[CK];
    __shared__ int dsts[CK];

    const int tid  = threadIdx.x;
    const int t    = blockIdx.x;
    const int head = blockIdx.y;

    const int* srcp = src + t * CK;
    const int* dstp = dst + t * CK;

    if (tid < 64) {  // wave 0 computes the softmax weights
        const int k = tid;
        float e = -3.0e38f;
        int dv = 0;
        if (k < CK) {
            const int sv = srcp[k];
            dv = dstp[k];
            e = s1[(size_t)head * nnodes + sv] + s2[(size_t)head * nnodes + dv];
            e = (e > 0.f) ? e : ALPHA * e;  // LeakyReLU
        }
        float m = e;
#pragma unroll
        for (int mm = 1; mm < 64; mm <<= 1) m = fmaxf(m, __shfl_xor(m, mm));
        float p = (k < CK) ? __expf(e - m) : 0.f;
        float s = p;
#pragma unroll
        for (int mm = 1; mm < 64; mm <<= 1) s += __shfl_xor(s, mm);
        if (k < CK) {
            wgt[k]  = p / s;
            dsts[k] = dv;
        }
    }
    __syncthreads();

    const int j = tid;  // 0..127
    const float* hh = hm + head * CHID;
    float acc = 0.f;
#pragma unroll
    for (int k = 0; k < CK; ++k)
        acc = fmaf(wgt[k], hh[(size_t)dsts[k] * rowstride + j], acc);

    const float o = (acc > 0.f) ? acc : (__expf(acc) - 1.f);  // ELU
    out[(size_t)t * outstride + head * CHID + j] = o;
}

// ---------------------------------------------------------------------------
extern "C" void kernel_launch(void* const* d_in, const int* in_sizes, int n_in,
                              void* d_out, int out_size, void* d_ws, size_t ws_size,
                              hipStream_t stream) {
    const float* feats = (const float*)d_in[0];
    const float* W1    = (const float*)d_in[1];
    const float* a1    = (const float*)d_in[2];
    const float* W2    = (const float*)d_in[3];
    const float* a2    = (const float*)d_in[4];
    const int*   src1  = (const int*)d_in[5];
    const int*   dst1  = (const int*)d_in[6];
    const int*   src2  = (const int*)d_in[8];
    const int*   dst2  = (const int*)d_in[9];
    float* out = (float*)d_out;

    float* ws  = (float*)d_ws;
    float* h1  = ws;                              // [8192][1024]
    float* s1  = h1 + (size_t)CN2 * (CNH * CHID); // [8][8192]
    float* s2  = s1 + (size_t)CNH * CN2;          // [8][8192]
    float* x   = s2 + (size_t)CNH * CN2;          // [2048][1024]
    float* h2  = x + (size_t)CN1 * (CNH * CHID);  // [2048][128]
    float* s21 = h2 + (size_t)CN1 * CHID;         // [2048]
    float* s22 = s21 + CN1;                       // [2048]

    // layer 1: h1 = feats @ W1 (all 8 heads as one [8192 x 1024] GEMM, K=256)
    gemm_tile<0><<<dim3(CN2 / 64, (CNH * CHID) / 64), 256, 0, stream>>>(
        feats, W1, h1, CN2, CNH * CHID, CIN);

    // per-(head,node) scores
    scores_k<<<dim3((CN2 * CNH) / 4), 256, 0, stream>>>(h1, a1, s1, s2, CN2, CNH, CNH * CHID);

    // softmax + aggregate + ELU -> x [2048][1024]
    agg_k<<<dim3(CN1, CNH), 128, 0, stream>>>(s1, s2, src1, dst1, h1, x,
                                              CN2, CNH * CHID, CNH * CHID);

    // layer 2: h2 = x @ W2 ([2048 x 128] GEMM, K=1024)
    gemm_tile<1><<<dim3(CN1 / 64, CHID / 64), 256, 0, stream>>>(x, W2, h2, CN1, CHID, CNH * CHID);

    scores_k<<<dim3(CN1 / 4), 256, 0, stream>>>(h2, a2, s21, s22, CN1, 1, CHID);

    agg_k<<<dim3(CN0, 1), 128, 0, stream>>>(s21, s22, src2, dst2, h2, out,
                                            CN1, CHID, CHID);
}

// Round 2
// 69.555 us; speedup vs baseline: 2.4459x; 2.4459x over previous
//
#include <hip/hip_runtime.h>
#include <math.h>

#define ALPHA 0.2f

constexpr int CN0 = 512, CN1 = 2048, CN2 = 8192, CK = 33;
constexpr int CIN = 256, CHID = 128, CNH = 8;

using u16   = unsigned short;
using f32x4 = __attribute__((ext_vector_type(4))) float;
using bf16x8 = __attribute__((ext_vector_type(8))) short;

__device__ __forceinline__ u16 f2bf(float f) {
    unsigned u = __float_as_uint(f);
    u += 0x7fff + ((u >> 16) & 1);   // RNE
    return (u16)(u >> 16);
}
__device__ __forceinline__ float bf2f(u16 h) {
    return __uint_as_float(((unsigned)h) << 16);
}

#define GLD16(g, l)                                                        \
    __builtin_amdgcn_global_load_lds(                                      \
        (const __attribute__((address_space(1))) void*)(g),                \
        (__attribute__((address_space(3))) void*)(l), 16, 0, 0)

// ---------------------------------------------------------------------------
// f32 -> bf16 straight convert (feats)
// ---------------------------------------------------------------------------
__global__ __launch_bounds__(256) void convbf(const float* __restrict__ in,
                                              u16* __restrict__ out, int n) {
    int i = (blockIdx.x * 256 + threadIdx.x) * 4;
    if (i < n) {
        float4 v = *reinterpret_cast<const float4*>(in + i);
        *reinterpret_cast<ushort4*>(out + i) =
            make_ushort4(f2bf(v.x), f2bf(v.y), f2bf(v.z), f2bf(v.w));
    }
}

// ---------------------------------------------------------------------------
// transpose + convert: in [H][R][C] f32 -> out [H][C][R] bf16
// grid (R/32, C/32, H), block 256
// ---------------------------------------------------------------------------
__global__ __launch_bounds__(256) void transconv(const float* __restrict__ in,
                                                 u16* __restrict__ out, int R, int C) {
    __shared__ float t[32][33];
    const float* ip = in + (size_t)blockIdx.z * R * C;
    u16* op = out + (size_t)blockIdx.z * R * C;
    const int r0 = blockIdx.x * 32, c0 = blockIdx.y * 32;
    const int tx = threadIdx.x & 31, ty = threadIdx.x >> 5;  // 32 x 8
#pragma unroll
    for (int i = 0; i < 4; ++i)
        t[ty + 8 * i][tx] = ip[(size_t)(r0 + ty + 8 * i) * C + c0 + tx];
    __syncthreads();
#pragma unroll
    for (int i = 0; i < 4; ++i)
        op[(size_t)(c0 + ty + 8 * i) * R + r0 + tx] = f2bf(t[tx][ty + 8 * i]);
}

// ---------------------------------------------------------------------------
// bf16 MFMA GEMM, 128x128 tile, BK=32, 4 waves (each 64x64 = 4x4 frags of
// 16x16x32).  A [M][lda] bf16 row-major; Bt [N][ldb] bf16 (B transposed,
// K contiguous).  Swizzled LDS: 16B chunk c of row r stored at c^=(c+(r>>1))&3
// so fragment ds_read_b128 is 2-way (free).  Staged with global_load_lds
// (linear dest, pre-swizzled global source).
// blockIdx.z = K-split (KSTEPS*32 elems each); C offset z*csplit.
// ---------------------------------------------------------------------------
template <int KSTEPS, bool BF16OUT>
__global__ __launch_bounds__(256) void gemm_mfma(const u16* __restrict__ A, int lda,
                                                 const u16* __restrict__ Bt, int ldb,
                                                 u16* __restrict__ Cb,
                                                 float* __restrict__ Cf, int ldc,
                                                 long csplit) {
    __shared__ __attribute__((aligned(16))) u16 As[128 * 32];
    __shared__ __attribute__((aligned(16))) u16 Bs[128 * 32];

    const int tid  = threadIdx.x;
    const int lane = tid & 63;
    const int wave = tid >> 6;
    const int row0 = blockIdx.x * 128;
    const int col0 = blockIdx.y * 128;
    const int kbase = blockIdx.z * (KSTEPS * 32);
    const int wr = (wave >> 1) * 64;
    const int wc = (wave & 1) * 64;

    f32x4 acc[4][4];
#pragma unroll
    for (int m = 0; m < 4; ++m)
#pragma unroll
        for (int n = 0; n < 4; ++n) acc[m][n] = (f32x4){0.f, 0.f, 0.f, 0.f};

    // staging: thread t handles 16B chunks t and t+256 of each 8KB tile.
    // chunk q: LDS row r=q>>2, stored slot cs=q&3, source k-chunk c=(cs-(r>>1))&3
    const int r0c = tid >> 2;
    const int cs0 = tid & 3;
    const int c0  = (cs0 - (r0c >> 1)) & 3;   // same for chunk1 (r+64 -> same &3)
    const int r1c = r0c + 64;

    const u16* ga0 = A + (size_t)(row0 + r0c) * lda + kbase + c0 * 8;
    const u16* ga1 = A + (size_t)(row0 + r1c) * lda + kbase + c0 * 8;
    const u16* gb0 = Bt + (size_t)(col0 + r0c) * ldb + kbase + c0 * 8;
    const u16* gb1 = Bt + (size_t)(col0 + r1c) * ldb + kbase + c0 * 8;
    u16* As0 = As + wave * 512;          // byte offset wave*1024, +lane*16 by HW
    u16* As1 = As + 2048 + wave * 512;
    u16* Bs0 = Bs + wave * 512;
    u16* Bs1 = Bs + 2048 + wave * 512;

    for (int s = 0; s < KSTEPS; ++s) {
        const int k0 = s * 32;
        GLD16(ga0 + k0, As0);
        GLD16(ga1 + k0, As1);
        GLD16(gb0 + k0, Bs0);
        GLD16(gb1 + k0, Bs1);
        __syncthreads();

        bf16x8 af[4], bfr[4];
#pragma unroll
        for (int m = 0; m < 4; ++m) {
            const int rt = wr + m * 16 + (lane & 15);
            const int cs = ((lane >> 4) + (rt >> 1)) & 3;
            af[m] = *reinterpret_cast<const bf16x8*>(&As[rt * 32 + cs * 8]);
            const int rt2 = wc + m * 16 + (lane & 15);
            const int cs2 = ((lane >> 4) + (rt2 >> 1)) & 3;
            bfr[m] = *reinterpret_cast<const bf16x8*>(&Bs[rt2 * 32 + cs2 * 8]);
        }
#pragma unroll
        for (int m = 0; m < 4; ++m)
#pragma unroll
            for (int n = 0; n < 4; ++n)
                acc[m][n] = __builtin_amdgcn_mfma_f32_16x16x32_bf16(
                    af[m], bfr[n], acc[m][n], 0, 0, 0);
        __syncthreads();
    }

    // C/D layout: col = lane&15, row = (lane>>4)*4 + q   [m89-verified]
    const long cbase = (long)blockIdx.z * csplit;
#pragma unroll
    for (int m = 0; m < 4; ++m) {
        const int rr = row0 + wr + m * 16 + (lane >> 4) * 4;
#pragma unroll
        for (int n = 0; n < 4; ++n) {
            const int cc = col0 + wc + n * 16 + (lane & 15);
#pragma unroll
            for (int q = 0; q < 4; ++q) {
                const long idx = cbase + (long)(rr + q) * ldc + cc;
                if (BF16OUT) Cb[idx] = f2bf(acc[m][n][q]);
                else         Cf[idx] = acc[m][n][q];
            }
        }
    }
}

// ---------------------------------------------------------------------------
// layer-1 scores from bf16 h1: one wave per (head,node); s[head][node]
// ---------------------------------------------------------------------------
__global__ __launch_bounds__(256) void scores1_k(const u16* __restrict__ hm,
                                                 const float* __restrict__ a,
                                                 float* __restrict__ s1,
                                                 float* __restrict__ s2) {
    const int wid  = (blockIdx.x * 256 + threadIdx.x) >> 6;   // head*8192+node
    const int lane = threadIdx.x & 63;
    const int head = wid >> 13;
    const int node = wid & (CN2 - 1);
    const int j = lane * 2;

    const unsigned hv = *reinterpret_cast<const unsigned*>(
        hm + (size_t)node * (CNH * CHID) + head * CHID + j);
    const float h0 = bf2f((u16)(hv & 0xffff)), h1 = bf2f((u16)(hv >> 16));
    const float* ah = a + head * 2 * CHID;
    float d1 = h0 * ah[j] + h1 * ah[j + 1];
    float d2 = h0 * ah[CHID + j] + h1 * ah[CHID + j + 1];
#pragma unroll
    for (int m = 1; m < 64; m <<= 1) {
        d1 += __shfl_xor(d1, m);
        d2 += __shfl_xor(d2, m);
    }
    if (lane == 0) { s1[wid] = d1; s2[wid] = d2; }
}

// ---------------------------------------------------------------------------
// layer-1 softmax+aggregate+ELU: one wave per (t,head); bf16 in, bf16 out
// ---------------------------------------------------------------------------
__global__ __launch_bounds__(256) void agg1_k(const float* __restrict__ s1,
                                              const float* __restrict__ s2,
                                              const int* __restrict__ src,
                                              const int* __restrict__ dst,
                                              const u16* __restrict__ hm,
                                              u16* __restrict__ xout) {
    const int wid  = (blockIdx.x * 256 + threadIdx.x) >> 6;
    const int lane = threadIdx.x & 63;
    const int head = wid & 7;
    const int t    = wid >> 3;

    float e = -3.0e38f;
    int dv = 0;
    if (lane < CK) {
        const int sv = src[t * CK + lane];
        dv = dst[t * CK + lane];
        const float ee = s1[head * CN2 + sv] + s2[head * CN2 + dv];
        e = (ee > 0.f) ? ee : ALPHA * ee;
    }
    float m = e;
#pragma unroll
    for (int mm = 1; mm < 64; mm <<= 1) m = fmaxf(m, __shfl_xor(m, mm));
    float p = (lane < CK) ? __expf(e - m) : 0.f;
    float ssum = p;
#pragma unroll
    for (int mm = 1; mm < 64; mm <<= 1) ssum += __shfl_xor(ssum, mm);
    const float invs = 1.f / ssum;

    float a0 = 0.f, a1 = 0.f;
#pragma unroll
    for (int k = 0; k < CK; ++k) {
        const float w = __shfl(p, k) * invs;
        const int d = __shfl(dv, k);
        const unsigned hv = *reinterpret_cast<const unsigned*>(
            hm + (size_t)d * (CNH * CHID) + head * CHID + lane * 2);
        a0 = fmaf(w, bf2f((u16)(hv & 0xffff)), a0);
        a1 = fmaf(w, bf2f((u16)(hv >> 16)), a1);
    }
    a0 = (a0 > 0.f) ? a0 : __expf(a0) - 1.f;   // ELU
    a1 = (a1 > 0.f) ? a1 : __expf(a1) - 1.f;
    const unsigned o = ((unsigned)f2bf(a1) << 16) | f2bf(a0);
    *reinterpret_cast<unsigned*>(xout + (size_t)t * (CNH * CHID) + head * CHID + lane * 2) = o;
}

// ---------------------------------------------------------------------------
// layer-2: reduce split-K partials -> h2 f32, + scores. one wave per node
// ---------------------------------------------------------------------------
__global__ __launch_bounds__(256) void scores2_k(const float* __restrict__ part,
                                                 const float* __restrict__ a,
                                                 float* __restrict__ h2,
                                                 float* __restrict__ s1,
                                                 float* __restrict__ s2) {
    const int wid  = (blockIdx.x * 256 + threadIdx.x) >> 6;   // node
    const int lane = threadIdx.x & 63;
    const int j = lane * 2;
    float x0 = 0.f, x1 = 0.f;
#pragma unroll
    for (int sp = 0; sp < 8; ++sp) {
        const float2 v = *reinterpret_cast<const float2*>(
            part + (size_t)sp * CN1 * CHID + (size_t)wid * CHID + j);
        x0 += v.x; x1 += v.y;
    }
    *reinterpret_cast<float2*>(h2 + (size_t)wid * CHID + j) = make_float2(x0, x1);
    float d1 = x0 * a[j] + x1 * a[j + 1];
    float d2 = x0 * a[CHID + j] + x1 * a[CHID + j + 1];
#pragma unroll
    for (int m = 1; m < 64; m <<= 1) {
        d1 += __shfl_xor(d1, m);
        d2 += __shfl_xor(d2, m);
    }
    if (lane == 0) { s1[wid] = d1; s2[wid] = d2; }
}

// ---------------------------------------------------------------------------
// layer-2 softmax+aggregate+ELU: one wave per target; f32 in/out
// ---------------------------------------------------------------------------
__global__ __launch_bounds__(256) void agg2_k(const float* __restrict__ s1,
                                              const float* __restrict__ s2,
                                              const int* __restrict__ src,
                                              const int* __restrict__ dst,
                                              const float* __restrict__ h2,
                                              float* __restrict__ out) {
    const int t    = (blockIdx.x * 256 + threadIdx.x) >> 6;
    const int lane = threadIdx.x & 63;

    float e = -3.0e38f;
    int dv = 0;
    if (lane < CK) {
        const int sv = src[t * CK + lane];
        dv = dst[t * CK + lane];
        const float ee = s1[sv] + s2[dv];
        e = (ee > 0.f) ? ee : ALPHA * ee;
    }
    float m = e;
#pragma unroll
    for (int mm = 1; mm < 64; mm <<= 1) m = fmaxf(m, __shfl_xor(m, mm));
    float p = (lane < CK) ? __expf(e - m) : 0.f;
    float ssum = p;
#pragma unroll
    for (int mm = 1; mm < 64; mm <<= 1) ssum += __shfl_xor(ssum, mm);
    const float invs = 1.f / ssum;

    float a0 = 0.f, a1 = 0.f;
#pragma unroll
    for (int k = 0; k < CK; ++k) {
        const float w = __shfl(p, k) * invs;
        const int d = __shfl(dv, k);
        const float2 hv = *reinterpret_cast<const float2*>(h2 + (size_t)d * CHID + lane * 2);
        a0 = fmaf(w, hv.x, a0);
        a1 = fmaf(w, hv.y, a1);
    }
    a0 = (a0 > 0.f) ? a0 : __expf(a0) - 1.f;
    a1 = (a1 > 0.f) ? a1 : __expf(a1) - 1.f;
    *reinterpret_cast<float2*>(out + (size_t)t * CHID + lane * 2) = make_float2(a0, a1);
}

// ---------------------------------------------------------------------------
extern "C" void kernel_launch(void* const* d_in, const int* in_sizes, int n_in,
                              void* d_out, int out_size, void* d_ws, size_t ws_size,
                              hipStream_t stream) {
    const float* feats = (const float*)d_in[0];
    const float* W1    = (const float*)d_in[1];
    const float* a1    = (const float*)d_in[2];
    const float* W2    = (const float*)d_in[3];
    const float* a2    = (const float*)d_in[4];
    const int*   src1  = (const int*)d_in[5];
    const int*   dst1  = (const int*)d_in[6];
    const int*   src2  = (const int*)d_in[8];
    const int*   dst2  = (const int*)d_in[9];
    float* out = (float*)d_out;

    char* w = (char*)d_ws;
    u16*   fb   = (u16*)w;                 w += (size_t)CN2 * CIN * 2;          // 4 MB
    u16*   w1t  = (u16*)w;                 w += (size_t)CNH * CIN * CHID * 2;   // 0.5 MB
    u16*   w2t  = (u16*)w;                 w += (size_t)CNH * CHID * CHID * 2;  // 0.25 MB
    u16*   h1b  = (u16*)w;                 w += (size_t)CN2 * CNH * CHID * 2;   // 16 MB
    float* s1   = (float*)w;               w += (size_t)CNH * CN2 * 4;
    float* s2   = (float*)w;               w += (size_t)CNH * CN2 * 4;
    u16*   xb   = (u16*)w;                 w += (size_t)CN1 * CNH * CHID * 2;   // 4 MB
    float* part = (float*)w;               w += (size_t)8 * CN1 * CHID * 4;     // 8 MB
    float* h2   = (float*)w;               w += (size_t)CN1 * CHID * 4;         // 1 MB
    float* s21  = (float*)w;               w += (size_t)CN1 * 4;
    float* s22  = (float*)w;               w += (size_t)CN1 * 4;

    // ---- convert inputs to bf16 (W's transposed so GEMM stages Bt) ----
    convbf<<<dim3((CN2 * CIN) / 1024), 256, 0, stream>>>(feats, fb, CN2 * CIN);
    transconv<<<dim3(CIN / 32, CHID / 32, CNH), 256, 0, stream>>>(W1, w1t, CIN, CHID);
    transconv<<<dim3((CNH * CHID) / 32, CHID / 32, 1), 256, 0, stream>>>(W2, w2t, CNH * CHID, CHID);

    // ---- layer 1: h1 = feats @ W1  (bf16 MFMA, out bf16) ----
    gemm_mfma<8, true><<<dim3(CN2 / 128, (CNH * CHID) / 128, 1), 256, 0, stream>>>(
        fb, CIN, w1t, CIN, h1b, nullptr, CNH * CHID, 0);

    scores1_k<<<dim3((CN2 * CNH) / 4), 256, 0, stream>>>(h1b, a1, s1, s2);

    agg1_k<<<dim3((CN1 * CNH) / 4), 256, 0, stream>>>(s1, s2, src1, dst1, h1b, xb);

    // ---- layer 2: h2 = x @ W2 (split-K=8 partials, f32) ----
    gemm_mfma<4, false><<<dim3(CN1 / 128, 1, 8), 256, 0, stream>>>(
        xb, CNH * CHID, w2t, CNH * CHID, nullptr, part, CHID, (long)CN1 * CHID);

    scores2_k<<<dim3(CN1 / 4), 256, 0, stream>>>(part, a2, h2, s21, s22);

    agg2_k<<<dim3(CN0 / 4), 256, 0, stream>>>(s21, s22, src2, dst2, h2, out);
}

// Round 3
// 65.058 us; speedup vs baseline: 2.6150x; 1.0691x over previous
//
#include <hip/hip_runtime.h>
#include <math.h>

#define ALPHA 0.2f

constexpr int CN0 = 512, CN1 = 2048, CN2 = 8192, CK = 33;
constexpr int CIN = 256, CHID = 128, CNH = 8;

using u16   = unsigned short;
using f32x4 = __attribute__((ext_vector_type(4))) float;
using bf16x8 = __attribute__((ext_vector_type(8))) short;

__device__ __forceinline__ u16 f2bf(float f) {
    unsigned u = __float_as_uint(f);
    u += 0x7fff + ((u >> 16) & 1);   // RNE
    return (u16)(u >> 16);
}
__device__ __forceinline__ float bf2f(u16 h) {
    return __uint_as_float(((unsigned)h) << 16);
}

#define GLD16(g, l)                                                        \
    __builtin_amdgcn_global_load_lds(                                      \
        (const __attribute__((address_space(1))) void*)(g),                \
        (__attribute__((address_space(3))) void*)(l), 16, 0, 0)

// ---------------------------------------------------------------------------
// f32 -> bf16 straight convert (feats)
// ---------------------------------------------------------------------------
__global__ __launch_bounds__(256) void convbf(const float* __restrict__ in,
                                              u16* __restrict__ out, int n) {
    int i = (blockIdx.x * 256 + threadIdx.x) * 4;
    if (i < n) {
        float4 v = *reinterpret_cast<const float4*>(in + i);
        *reinterpret_cast<ushort4*>(out + i) =
            make_ushort4(f2bf(v.x), f2bf(v.y), f2bf(v.z), f2bf(v.w));
    }
}

// ---------------------------------------------------------------------------
// transpose + convert: in [H][R][C] f32 -> out [H][C][R] bf16
// ---------------------------------------------------------------------------
__global__ __launch_bounds__(256) void transconv(const float* __restrict__ in,
                                                 u16* __restrict__ out, int R, int C) {
    __shared__ float t[32][33];
    const float* ip = in + (size_t)blockIdx.z * R * C;
    u16* op = out + (size_t)blockIdx.z * R * C;
    const int r0 = blockIdx.x * 32, c0 = blockIdx.y * 32;
    const int tx = threadIdx.x & 31, ty = threadIdx.x >> 5;  // 32 x 8
#pragma unroll
    for (int i = 0; i < 4; ++i)
        t[ty + 8 * i][tx] = ip[(size_t)(r0 + ty + 8 * i) * C + c0 + tx];
    __syncthreads();
#pragma unroll
    for (int i = 0; i < 4; ++i)
        op[(size_t)(c0 + ty + 8 * i) * R + r0 + tx] = f2bf(t[tx][ty + 8 * i]);
}

// ---------------------------------------------------------------------------
// bf16 MFMA GEMM, 128x128 tile, BK=32, 4 waves.
// SCORES: fused per-row dual dot with attention vector a (tile col-range ==
// one full head), emitting s1/s2 — only valid when N-tile == CHID.
// ---------------------------------------------------------------------------
template <int KSTEPS, bool BF16OUT, bool SCORES>
__global__ __launch_bounds__(256) void gemm_mfma(const u16* __restrict__ A, int lda,
                                                 const u16* __restrict__ Bt, int ldb,
                                                 u16* __restrict__ Cb,
                                                 float* __restrict__ Cf, int ldc,
                                                 long csplit,
                                                 const float* __restrict__ av,
                                                 float* __restrict__ s1o,
                                                 float* __restrict__ s2o) {
    __shared__ __attribute__((aligned(16))) u16 As[128 * 32];
    __shared__ __attribute__((aligned(16))) u16 Bs[128 * 32];
    __shared__ float sred1[2][128];
    __shared__ float sred2[2][128];

    const int tid  = threadIdx.x;
    const int lane = tid & 63;
    const int wave = tid >> 6;
    const int row0 = blockIdx.x * 128;
    const int col0 = blockIdx.y * 128;
    const int kbase = blockIdx.z * (KSTEPS * 32);
    const int wr = (wave >> 1) * 64;
    const int wc = (wave & 1) * 64;

    f32x4 acc[4][4];
#pragma unroll
    for (int m = 0; m < 4; ++m)
#pragma unroll
        for (int n = 0; n < 4; ++n) acc[m][n] = (f32x4){0.f, 0.f, 0.f, 0.f};

    // staging: swizzled source chunk so ds_read_b128 fragments are ~free
    const int r0c = tid >> 2;
    const int cs0 = tid & 3;
    const int c0  = (cs0 - (r0c >> 1)) & 3;
    const int r1c = r0c + 64;

    const u16* ga0 = A + (size_t)(row0 + r0c) * lda + kbase + c0 * 8;
    const u16* ga1 = A + (size_t)(row0 + r1c) * lda + kbase + c0 * 8;
    const u16* gb0 = Bt + (size_t)(col0 + r0c) * ldb + kbase + c0 * 8;
    const u16* gb1 = Bt + (size_t)(col0 + r1c) * ldb + kbase + c0 * 8;
    u16* As0 = As + wave * 512;
    u16* As1 = As + 2048 + wave * 512;
    u16* Bs0 = Bs + wave * 512;
    u16* Bs1 = Bs + 2048 + wave * 512;

    for (int s = 0; s < KSTEPS; ++s) {
        const int k0 = s * 32;
        GLD16(ga0 + k0, As0);
        GLD16(ga1 + k0, As1);
        GLD16(gb0 + k0, Bs0);
        GLD16(gb1 + k0, Bs1);
        __syncthreads();

        bf16x8 af[4], bfr[4];
#pragma unroll
        for (int m = 0; m < 4; ++m) {
            const int rt = wr + m * 16 + (lane & 15);
            const int cs = ((lane >> 4) + (rt >> 1)) & 3;
            af[m] = *reinterpret_cast<const bf16x8*>(&As[rt * 32 + cs * 8]);
            const int rt2 = wc + m * 16 + (lane & 15);
            const int cs2 = ((lane >> 4) + (rt2 >> 1)) & 3;
            bfr[m] = *reinterpret_cast<const bf16x8*>(&Bs[rt2 * 32 + cs2 * 8]);
        }
#pragma unroll
        for (int m = 0; m < 4; ++m)
#pragma unroll
            for (int n = 0; n < 4; ++n)
                acc[m][n] = __builtin_amdgcn_mfma_f32_16x16x32_bf16(
                    af[m], bfr[n], acc[m][n], 0, 0, 0);
        __syncthreads();
    }

    // C/D layout: col = lane&15, row = (lane>>4)*4 + q   [m89-verified]
    const long cbase = (long)blockIdx.z * csplit;
#pragma unroll
    for (int m = 0; m < 4; ++m) {
        const int rr = row0 + wr + m * 16 + (lane >> 4) * 4;
#pragma unroll
        for (int n = 0; n < 4; ++n) {
            const int cc = col0 + wc + n * 16 + (lane & 15);
#pragma unroll
            for (int q = 0; q < 4; ++q) {
                const long idx = cbase + (long)(rr + q) * ldc + cc;
                if (BF16OUT) Cb[idx] = f2bf(acc[m][n][q]);
                else         Cf[idx] = acc[m][n][q];
            }
        }
    }

    if (SCORES) {
        // head == blockIdx.y (tile spans exactly one head's 128 cols)
        const int head = blockIdx.y;
        float av1[4], av2[4];
#pragma unroll
        for (int n = 0; n < 4; ++n) {
            const int c = wc + n * 16 + (lane & 15);
            av1[n] = av[head * 2 * CHID + c];
            av2[n] = av[head * 2 * CHID + CHID + c];
        }
        float p1[4][4], p2[4][4];
#pragma unroll
        for (int m = 0; m < 4; ++m)
#pragma unroll
            for (int q = 0; q < 4; ++q) {
                float t1 = 0.f, t2 = 0.f;
#pragma unroll
                for (int n = 0; n < 4; ++n) {
                    t1 = fmaf(acc[m][n][q], av1[n], t1);
                    t2 = fmaf(acc[m][n][q], av2[n], t2);
                }
#pragma unroll
                for (int mk = 1; mk < 16; mk <<= 1) {
                    t1 += __shfl_xor(t1, mk);
                    t2 += __shfl_xor(t2, mk);
                }
                p1[m][q] = t1;
                p2[m][q] = t2;
            }
        if ((lane & 15) == 0) {
            const int g = lane >> 4;
#pragma unroll
            for (int m = 0; m < 4; ++m)
#pragma unroll
                for (int q = 0; q < 4; ++q) {
                    sred1[wave & 1][wr + m * 16 + g * 4 + q] = p1[m][q];
                    sred2[wave & 1][wr + m * 16 + g * 4 + q] = p2[m][q];
                }
        }
        __syncthreads();
        if (tid < 128) {
            s1o[head * CN2 + row0 + tid] = sred1[0][tid] + sred1[1][tid];
            s2o[head * CN2 + row0 + tid] = sred2[0][tid] + sred2[1][tid];
        }
    }
}

// ---------------------------------------------------------------------------
// layer-1 softmax + aggregate + ELU.  One 256-thread block per target:
// phase 1: 8 head-softmaxes (wave w -> heads 2w, 2w+1) into LDS wgt[8][33]
// phase 2: 33 full-row (2KB) coalesced gathers, each thread owns 4 cols
// ---------------------------------------------------------------------------
__global__ __launch_bounds__(256) void agg1_k(const float* __restrict__ s1,
                                              const float* __restrict__ s2,
                                              const int* __restrict__ src,
                                              const int* __restrict__ dst,
                                              const u16* __restrict__ hm,
                                              u16* __restrict__ xout) {
    __shared__ float wgt[CNH][CK];
    __shared__ int dsts[CK];

    const int t    = blockIdx.x;
    const int tid  = threadIdx.x;
    const int wv   = tid >> 6;
    const int lane = tid & 63;

    int sv = 0, dv = 0;
    if (lane < CK) {
        sv = src[t * CK + lane];
        dv = dst[t * CK + lane];
        if (tid < CK) dsts[tid] = dv;
    }
#pragma unroll
    for (int hh = 0; hh < 2; ++hh) {
        const int head = wv * 2 + hh;
        float e = -3.0e38f;
        if (lane < CK) {
            const float ee = s1[head * CN2 + sv] + s2[head * CN2 + dv];
            e = (ee > 0.f) ? ee : ALPHA * ee;
        }
        float m = e;
#pragma unroll
        for (int mm = 1; mm < 64; mm <<= 1) m = fmaxf(m, __shfl_xor(m, mm));
        const float p = (lane < CK) ? __expf(e - m) : 0.f;
        float s = p;
#pragma unroll
        for (int mm = 1; mm < 64; mm <<= 1) s += __shfl_xor(s, mm);
        if (lane < CK) wgt[head][lane] = p / s;
    }
    __syncthreads();

    const int head = tid >> 5;  // 4 cols/thread, 128 cols per head
    float a0 = 0.f, a1 = 0.f, a2 = 0.f, a3 = 0.f;
#pragma unroll
    for (int k = 0; k < CK; ++k) {
        const float w = wgt[head][k];
        const ushort4 hv = *reinterpret_cast<const ushort4*>(
            hm + (size_t)dsts[k] * (CNH * CHID) + tid * 4);
        a0 = fmaf(w, bf2f(hv.x), a0);
        a1 = fmaf(w, bf2f(hv.y), a1);
        a2 = fmaf(w, bf2f(hv.z), a2);
        a3 = fmaf(w, bf2f(hv.w), a3);
    }
    a0 = (a0 > 0.f) ? a0 : __expf(a0) - 1.f;
    a1 = (a1 > 0.f) ? a1 : __expf(a1) - 1.f;
    a2 = (a2 > 0.f) ? a2 : __expf(a2) - 1.f;
    a3 = (a3 > 0.f) ? a3 : __expf(a3) - 1.f;
    *reinterpret_cast<ushort4*>(xout + (size_t)t * (CNH * CHID) + tid * 4) =
        make_ushort4(f2bf(a0), f2bf(a1), f2bf(a2), f2bf(a3));
}

// ---------------------------------------------------------------------------
// layer-2: reduce split-K partials -> h2 f32, + scores. one wave per node
// ---------------------------------------------------------------------------
__global__ __launch_bounds__(256) void scores2_k(const float* __restrict__ part,
                                                 const float* __restrict__ a,
                                                 float* __restrict__ h2,
                                                 float* __restrict__ s1,
                                                 float* __restrict__ s2) {
    const int wid  = (blockIdx.x * 256 + threadIdx.x) >> 6;   // node
    const int lane = threadIdx.x & 63;
    const int j = lane * 2;
    float x0 = 0.f, x1 = 0.f;
#pragma unroll
    for (int sp = 0; sp < 8; ++sp) {
        const float2 v = *reinterpret_cast<const float2*>(
            part + (size_t)sp * CN1 * CHID + (size_t)wid * CHID + j);
        x0 += v.x; x1 += v.y;
    }
    *reinterpret_cast<float2*>(h2 + (size_t)wid * CHID + j) = make_float2(x0, x1);
    float d1 = x0 * a[j] + x1 * a[j + 1];
    float d2 = x0 * a[CHID + j] + x1 * a[CHID + j + 1];
#pragma unroll
    for (int m = 1; m < 64; m <<= 1) {
        d1 += __shfl_xor(d1, m);
        d2 += __shfl_xor(d2, m);
    }
    if (lane == 0) { s1[wid] = d1; s2[wid] = d2; }
}

// ---------------------------------------------------------------------------
// layer-2 softmax+aggregate+ELU: one wave per target; f32 in/out
// ---------------------------------------------------------------------------
__global__ __launch_bounds__(256) void agg2_k(const float* __restrict__ s1,
                                              const float* __restrict__ s2,
                                              const int* __restrict__ src,
                                              const int* __restrict__ dst,
                                              const float* __restrict__ h2,
                                              float* __restrict__ out) {
    const int t    = (blockIdx.x * 256 + threadIdx.x) >> 6;
    const int lane = threadIdx.x & 63;

    float e = -3.0e38f;
    int dv = 0;
    if (lane < CK) {
        const int sv = src[t * CK + lane];
        dv = dst[t * CK + lane];
        const float ee = s1[sv] + s2[dv];
        e = (ee > 0.f) ? ee : ALPHA * ee;
    }
    float m = e;
#pragma unroll
    for (int mm = 1; mm < 64; mm <<= 1) m = fmaxf(m, __shfl_xor(m, mm));
    float p = (lane < CK) ? __expf(e - m) : 0.f;
    float ssum = p;
#pragma unroll
    for (int mm = 1; mm < 64; mm <<= 1) ssum += __shfl_xor(ssum, mm);
    const float invs = 1.f / ssum;

    float a0 = 0.f, a1 = 0.f;
#pragma unroll
    for (int k = 0; k < CK; ++k) {
        const float w = __shfl(p, k) * invs;
        const int d = __shfl(dv, k);
        const float2 hv = *reinterpret_cast<const float2*>(h2 + (size_t)d * CHID + lane * 2);
        a0 = fmaf(w, hv.x, a0);
        a1 = fmaf(w, hv.y, a1);
    }
    a0 = (a0 > 0.f) ? a0 : __expf(a0) - 1.f;
    a1 = (a1 > 0.f) ? a1 : __expf(a1) - 1.f;
    *reinterpret_cast<float2*>(out + (size_t)t * CHID + lane * 2) = make_float2(a0, a1);
}

// ---------------------------------------------------------------------------
extern "C" void kernel_launch(void* const* d_in, const int* in_sizes, int n_in,
                              void* d_out, int out_size, void* d_ws, size_t ws_size,
                              hipStream_t stream) {
    const float* feats = (const float*)d_in[0];
    const float* W1    = (const float*)d_in[1];
    const float* a1    = (const float*)d_in[2];
    const float* W2    = (const float*)d_in[3];
    const float* a2    = (const float*)d_in[4];
    const int*   src1  = (const int*)d_in[5];
    const int*   dst1  = (const int*)d_in[6];
    const int*   src2  = (const int*)d_in[8];
    const int*   dst2  = (const int*)d_in[9];
    float* out = (float*)d_out;

    char* w = (char*)d_ws;
    u16*   fb   = (u16*)w;                 w += (size_t)CN2 * CIN * 2;
    u16*   w1t  = (u16*)w;                 w += (size_t)CNH * CIN * CHID * 2;
    u16*   w2t  = (u16*)w;                 w += (size_t)CNH * CHID * CHID * 2;
    u16*   h1b  = (u16*)w;                 w += (size_t)CN2 * CNH * CHID * 2;
    float* s1   = (float*)w;               w += (size_t)CNH * CN2 * 4;
    float* s2   = (float*)w;               w += (size_t)CNH * CN2 * 4;
    u16*   xb   = (u16*)w;                 w += (size_t)CN1 * CNH * CHID * 2;
    float* part = (float*)w;               w += (size_t)8 * CN1 * CHID * 4;
    float* h2   = (float*)w;               w += (size_t)CN1 * CHID * 4;
    float* s21  = (float*)w;               w += (size_t)CN1 * 4;
    float* s22  = (float*)w;               w += (size_t)CN1 * 4;

    // ---- convert inputs to bf16 (W's transposed so GEMM stages Bt) ----
    convbf<<<dim3((CN2 * CIN) / 1024), 256, 0, stream>>>(feats, fb, CN2 * CIN);
    transconv<<<dim3(CIN / 32, CHID / 32, CNH), 256, 0, stream>>>(W1, w1t, CIN, CHID);
    transconv<<<dim3((CNH * CHID) / 32, CHID / 32, 1), 256, 0, stream>>>(W2, w2t, CNH * CHID, CHID);

    // ---- layer 1: h1 = feats @ W1 (bf16 out) + fused s1/s2 scores ----
    gemm_mfma<8, true, true><<<dim3(CN2 / 128, (CNH * CHID) / 128, 1), 256, 0, stream>>>(
        fb, CIN, w1t, CIN, h1b, nullptr, CNH * CHID, 0, a1, s1, s2);

    // ---- layer-1 softmax + aggregate + ELU (block per target) ----
    agg1_k<<<dim3(CN1), 256, 0, stream>>>(s1, s2, src1, dst1, h1b, xb);

    // ---- layer 2: h2 = x @ W2 (split-K=8 partials, f32) ----
    gemm_mfma<4, false, false><<<dim3(CN1 / 128, 1, 8), 256, 0, stream>>>(
        xb, CNH * CHID, w2t, CNH * CHID, nullptr, part, CHID, (long)CN1 * CHID,
        nullptr, nullptr, nullptr);

    scores2_k<<<dim3(CN1 / 4), 256, 0, stream>>>(part, a2, h2, s21, s22);

    agg2_k<<<dim3(CN0 / 4), 256, 0, stream>>>(s21, s22, src2, dst2, h2, out);
}